// Round 1
// baseline (5461.012 us; speedup 1.0000x reference)
//
#include <hip/hip_runtime.h>
#include <math.h>

// Problem constants
#define BB    2
#define NN    1024
#define CC    768
#define HH    12
#define HPP   24
#define HD    64
#define SCALE 0.125f

// workspace layout (floats)
#define SEG   (2*1024*768)   // 1,572,864 floats per tensor
#define QOFF  0
#define KOFF  (SEG)
#define VOFF  (2*SEG)
#define HOFF  (3*SEG)

// ---------------------------------------------------------------------------
// Kernel 1: fused QKV projection.  x(2048,768) @ [Wqk;Wv]^T -> q,k,v in
// (B,H,N,HD) layout.  64x64x16 tiled fp32 GEMM, 256 threads, 4x4 microtile.
// ---------------------------------------------------------------------------
__global__ __launch_bounds__(256)
void qkv_gemm(const float* __restrict__ x, const float* __restrict__ Wqk,
              const float* __restrict__ Wv, float* __restrict__ ws)
{
    __shared__ float As[16][68];   // [k][m], +4 pad keeps 16B alignment
    __shared__ float Bs[16][68];
    float* qws = ws + QOFF;
    float* kws = ws + KOFF;
    float* vws = ws + VOFF;

    const int tid  = threadIdx.x;
    const int bn   = blockIdx.x;        // 0..35 (2304 cols / 64)
    const int bm   = blockIdx.y;        // 0..31 (2048 rows / 64)
    const int tx   = tid & 15, ty = tid >> 4;
    const int lrow = tid >> 2;          // 0..63
    const int lk   = (tid & 3) << 2;    // 0,4,8,12

    const int jrow = bn * 64 + lrow;    // weight row (output column)
    const float* Bsrc = (jrow < 1536) ? (Wqk + (size_t)jrow * 768)
                                      : (Wv  + (size_t)(jrow - 1536) * 768);
    const float* Asrc = x + (size_t)(bm * 64 + lrow) * 768;

    float c[4][4] = {};

    for (int k0 = 0; k0 < 768; k0 += 16) {
        float4 av = *(const float4*)(Asrc + k0 + lk);
        float4 bv = *(const float4*)(Bsrc + k0 + lk);
        __syncthreads();
        As[lk+0][lrow] = av.x; As[lk+1][lrow] = av.y;
        As[lk+2][lrow] = av.z; As[lk+3][lrow] = av.w;
        Bs[lk+0][lrow] = bv.x; Bs[lk+1][lrow] = bv.y;
        Bs[lk+2][lrow] = bv.z; Bs[lk+3][lrow] = bv.w;
        __syncthreads();
#pragma unroll
        for (int kk = 0; kk < 16; ++kk) {
            float a[4], b[4];
#pragma unroll
            for (int i = 0; i < 4; ++i) a[i] = As[kk][ty*4 + i];
#pragma unroll
            for (int j = 0; j < 4; ++j) b[j] = Bs[kk][tx*4 + j];
#pragma unroll
            for (int i = 0; i < 4; ++i)
#pragma unroll
                for (int j = 0; j < 4; ++j)
                    c[i][j] = fmaf(a[i], b[j], c[i][j]);
        }
    }

#pragma unroll
    for (int i = 0; i < 4; ++i) {
        const int t = bm*64 + ty*4 + i;      // token row
        const int b = t >> 10, n = t & 1023;
#pragma unroll
        for (int j = 0; j < 4; ++j) {
            const int col = bn*64 + tx*4 + j;
            float val = c[i][j];
            float* dst; int p;
            if (col < 768)       { p = col;        dst = qws; }
            else if (col < 1536) { p = col - 768;  dst = kws; }
            else                 { p = col - 1536; dst = vws; }
            dst[(((size_t)b*HH + (p >> 6))*NN + n)*HD + (p & 63)] = val;
        }
    }
}

// ---------------------------------------------------------------------------
// Kernel 2: per (b,n): 12 heads of QK^T logits -> softmax -> 1x1 expand
// (H->HP) -> write A_exp to d_out.  attn never materialized in HBM.
// ---------------------------------------------------------------------------
__global__ __launch_bounds__(256)
void attn_expand(const float* __restrict__ ws, const float* __restrict__ Wexp,
                 float* __restrict__ aexp)
{
    const float* q = ws + QOFF;
    const float* k = ws + KOFF;

    __shared__ float attn_s[HH * NN];            // 48 KB
    __shared__ __align__(16) float qs[HH * HD];  // 3 KB
    __shared__ float wexp_s[HPP * HH];
    __shared__ float red_s[4];

    const int tid = threadIdx.x;
    const int b = blockIdx.x >> 10, n = blockIdx.x & 1023;

    for (int idx = tid; idx < HH*HD; idx += 256) {
        int h = idx >> 6, d = idx & 63;
        qs[idx] = q[(((size_t)b*HH + h)*NN + n)*HD + d];
    }
    for (int idx = tid; idx < HPP*HH; idx += 256) wexp_s[idx] = Wexp[idx];
    __syncthreads();

    // logits (each thread owns 4 m-columns)
#pragma unroll
    for (int m0 = 0; m0 < 4; ++m0) {
        const int m = m0*256 + tid;
#pragma unroll
        for (int h = 0; h < HH; ++h) {
            const float4* kr = (const float4*)(k + (((size_t)b*HH + h)*NN + m)*HD);
            const float4* qr = (const float4*)(qs + h*HD);
            float acc = 0.f;
#pragma unroll
            for (int dd = 0; dd < 16; ++dd) {
                float4 kv = kr[dd], qv = qr[dd];
                acc += kv.x*qv.x + kv.y*qv.y + kv.z*qv.z + kv.w*qv.w;
            }
            attn_s[h*NN + m] = acc * SCALE;
        }
    }

    // softmax per head row
    for (int h = 0; h < HH; ++h) {
        float lm = -1e30f;
#pragma unroll
        for (int m0 = 0; m0 < 4; ++m0)
            lm = fmaxf(lm, attn_s[h*NN + m0*256 + tid]);
        for (int off = 32; off > 0; off >>= 1) lm = fmaxf(lm, __shfl_xor(lm, off, 64));
        if ((tid & 63) == 0) red_s[tid >> 6] = lm;
        __syncthreads();
        const float rowmax = fmaxf(fmaxf(red_s[0], red_s[1]), fmaxf(red_s[2], red_s[3]));
        __syncthreads();

        float ls = 0.f;
#pragma unroll
        for (int m0 = 0; m0 < 4; ++m0) {
            const int idx = h*NN + m0*256 + tid;
            const float e = __expf(attn_s[idx] - rowmax);
            attn_s[idx] = e; ls += e;
        }
        for (int off = 32; off > 0; off >>= 1) ls += __shfl_xor(ls, off, 64);
        if ((tid & 63) == 0) red_s[tid >> 6] = ls;
        __syncthreads();
        const float inv = 1.f / (red_s[0] + red_s[1] + red_s[2] + red_s[3]);
        __syncthreads();
#pragma unroll
        for (int m0 = 0; m0 < 4; ++m0)
            attn_s[h*NN + m0*256 + tid] *= inv;
    }
    __syncthreads();

    // expand H -> HP and write A_exp
    for (int o = 0; o < HPP; ++o) {
        float w[HH];
#pragma unroll
        for (int h = 0; h < HH; ++h) w[h] = wexp_s[o*HH + h];
        const size_t base = (((size_t)b*HPP + o)*NN + n)*NN;
#pragma unroll
        for (int m0 = 0; m0 < 4; ++m0) {
            const int m = m0*256 + tid;
            float acc = 0.f;
#pragma unroll
            for (int h = 0; h < HH; ++h) acc = fmaf(w[h], attn_s[h*NN + m], acc);
            aexp[base + m] = acc;
        }
    }
}

// ---------------------------------------------------------------------------
// Kernel 3: per (b,n): depthwise 3x3 conv (+bias,ReLU) over A_exp, reduce
// HP->H (*SCALE folded into wred), softmax, then attn2 @ v -> head_out in ws.
// A_loc / A_red / attn2 never materialized.
// ---------------------------------------------------------------------------
__global__ __launch_bounds__(256)
void conv_red_pv(const float* __restrict__ aexp, const float* __restrict__ Wloc,
                 const float* __restrict__ bloc, const float* __restrict__ Wred,
                 const float* __restrict__ vws, float* __restrict__ hout)
{
    __shared__ float ared[HH * NN];     // 48 KB (A_red, then attn2 in-place)
    __shared__ float rows[3][NN + 2];   // 12.3 KB, zero-padded edges
    __shared__ float wloc_s[HPP * 9];
    __shared__ float bloc_s[HPP];
    __shared__ float wred_s[HH * HPP];
    __shared__ float red_s[4];

    const int tid = threadIdx.x;
    const int b = blockIdx.x >> 10, n = blockIdx.x & 1023;

    for (int idx = tid; idx < HH*NN; idx += 256) ared[idx] = 0.f;
    for (int idx = tid; idx < HPP*9; idx += 256) wloc_s[idx] = Wloc[idx];
    if (tid < HPP) bloc_s[tid] = bloc[tid];
    for (int idx = tid; idx < HH*HPP; idx += 256) wred_s[idx] = Wred[idx] * SCALE;
    if (tid < 3) { rows[tid][0] = 0.f; rows[tid][NN+1] = 0.f; }
    __syncthreads();

    for (int o = 0; o < HPP; ++o) {
        // stage 3 input rows (n-1, n, n+1), zero rows out of range
        for (int r = 0; r < 3; ++r) {
            const int nr = n - 1 + r;
            if (nr >= 0 && nr < NN) {
                const float* src = aexp + (((size_t)b*HPP + o)*NN + nr)*NN;
#pragma unroll
                for (int m0 = 0; m0 < 4; ++m0) rows[r][1 + m0*256 + tid] = src[m0*256 + tid];
            } else {
#pragma unroll
                for (int m0 = 0; m0 < 4; ++m0) rows[r][1 + m0*256 + tid] = 0.f;
            }
        }
        __syncthreads();

        const float* w = wloc_s + o*9;
        const float bbias = bloc_s[o];
        float wr[HH];
#pragma unroll
        for (int i = 0; i < HH; ++i) wr[i] = wred_s[i*HPP + o];

#pragma unroll
        for (int m0 = 0; m0 < 4; ++m0) {
            const int m = m0*256 + tid;
            float acc = bbias;
            acc = fmaf(rows[0][m+0], w[0], acc);
            acc = fmaf(rows[0][m+1], w[1], acc);
            acc = fmaf(rows[0][m+2], w[2], acc);
            acc = fmaf(rows[1][m+0], w[3], acc);
            acc = fmaf(rows[1][m+1], w[4], acc);
            acc = fmaf(rows[1][m+2], w[5], acc);
            acc = fmaf(rows[2][m+0], w[6], acc);
            acc = fmaf(rows[2][m+1], w[7], acc);
            acc = fmaf(rows[2][m+2], w[8], acc);
            const float val = fmaxf(acc, 0.f);
#pragma unroll
            for (int i = 0; i < HH; ++i)
                ared[i*NN + m] = fmaf(wr[i], val, ared[i*NN + m]);
        }
        __syncthreads();
    }

    // softmax per head row of ared
    for (int i = 0; i < HH; ++i) {
        float lm = -1e30f;
#pragma unroll
        for (int m0 = 0; m0 < 4; ++m0)
            lm = fmaxf(lm, ared[i*NN + m0*256 + tid]);
        for (int off = 32; off > 0; off >>= 1) lm = fmaxf(lm, __shfl_xor(lm, off, 64));
        if ((tid & 63) == 0) red_s[tid >> 6] = lm;
        __syncthreads();
        const float rowmax = fmaxf(fmaxf(red_s[0], red_s[1]), fmaxf(red_s[2], red_s[3]));
        __syncthreads();

        float ls = 0.f;
#pragma unroll
        for (int m0 = 0; m0 < 4; ++m0) {
            const int idx = i*NN + m0*256 + tid;
            const float e = __expf(ared[idx] - rowmax);
            ared[idx] = e; ls += e;
        }
        for (int off = 32; off > 0; off >>= 1) ls += __shfl_xor(ls, off, 64);
        if ((tid & 63) == 0) red_s[tid >> 6] = ls;
        __syncthreads();
        const float inv = 1.f / (red_s[0] + red_s[1] + red_s[2] + red_s[3]);
        __syncthreads();
#pragma unroll
        for (int m0 = 0; m0 < 4; ++m0)
            ared[i*NN + m0*256 + tid] *= inv;
    }
    __syncthreads();

    // PV: lanes over d (coalesced v), wave-uniform attn2 broadcast from LDS
    const int g = tid >> 6, d = tid & 63;
    const int i0 = g, i1 = g + 4, i2 = g + 8;
    const float* v0 = vws + (((size_t)b*HH + i0)*NN)*HD + d;
    const float* v1 = vws + (((size_t)b*HH + i1)*NN)*HD + d;
    const float* v2 = vws + (((size_t)b*HH + i2)*NN)*HD + d;
    float acc0 = 0.f, acc1 = 0.f, acc2 = 0.f;
#pragma unroll 4
    for (int m = 0; m < NN; ++m) {
        acc0 = fmaf(ared[i0*NN + m], v0[(size_t)m*HD], acc0);
        acc1 = fmaf(ared[i1*NN + m], v1[(size_t)m*HD], acc1);
        acc2 = fmaf(ared[i2*NN + m], v2[(size_t)m*HD], acc2);
    }
    const size_t base = ((size_t)(b*NN + n)) * CC;
    hout[base + i0*HD + d] = acc0;
    hout[base + i1*HD + d] = acc1;
    hout[base + i2*HD + d] = acc2;
}

// ---------------------------------------------------------------------------
// Kernel 4: final projection  out = head_out @ Wproj^T + bias
// ---------------------------------------------------------------------------
__global__ __launch_bounds__(256)
void proj_gemm(const float* __restrict__ A, const float* __restrict__ Wp,
               const float* __restrict__ bias, float* __restrict__ out)
{
    __shared__ float As[16][68];
    __shared__ float Bs[16][68];

    const int tid  = threadIdx.x;
    const int bn   = blockIdx.x;   // 0..11
    const int bm   = blockIdx.y;   // 0..31
    const int tx   = tid & 15, ty = tid >> 4;
    const int lrow = tid >> 2;
    const int lk   = (tid & 3) << 2;

    const float* Asrc = A  + (size_t)(bm*64 + lrow) * 768;
    const float* Bsrc = Wp + (size_t)(bn*64 + lrow) * 768;

    float c[4][4] = {};

    for (int k0 = 0; k0 < 768; k0 += 16) {
        float4 av = *(const float4*)(Asrc + k0 + lk);
        float4 bv = *(const float4*)(Bsrc + k0 + lk);
        __syncthreads();
        As[lk+0][lrow] = av.x; As[lk+1][lrow] = av.y;
        As[lk+2][lrow] = av.z; As[lk+3][lrow] = av.w;
        Bs[lk+0][lrow] = bv.x; Bs[lk+1][lrow] = bv.y;
        Bs[lk+2][lrow] = bv.z; Bs[lk+3][lrow] = bv.w;
        __syncthreads();
#pragma unroll
        for (int kk = 0; kk < 16; ++kk) {
            float a[4], b[4];
#pragma unroll
            for (int i = 0; i < 4; ++i) a[i] = As[kk][ty*4 + i];
#pragma unroll
            for (int j = 0; j < 4; ++j) b[j] = Bs[kk][tx*4 + j];
#pragma unroll
            for (int i = 0; i < 4; ++i)
#pragma unroll
                for (int j = 0; j < 4; ++j)
                    c[i][j] = fmaf(a[i], b[j], c[i][j]);
        }
    }

#pragma unroll
    for (int i = 0; i < 4; ++i) {
        const int t = bm*64 + ty*4 + i;
#pragma unroll
        for (int j = 0; j < 4; ++j) {
            const int col = bn*64 + tx*4 + j;
            out[(size_t)t*768 + col] = c[i][j] + bias[col];
        }
    }
}

// ---------------------------------------------------------------------------
extern "C" void kernel_launch(void* const* d_in, const int* in_sizes, int n_in,
                              void* d_out, int out_size, void* d_ws, size_t ws_size,
                              hipStream_t stream)
{
    const float* x     = (const float*)d_in[0];
    const float* Wqk   = (const float*)d_in[1];
    const float* Wv    = (const float*)d_in[2];
    const float* Wexp  = (const float*)d_in[3];
    const float* Wloc  = (const float*)d_in[4];
    const float* bloc  = (const float*)d_in[5];
    const float* Wred  = (const float*)d_in[6];
    const float* Wproj = (const float*)d_in[7];
    const float* bproj = (const float*)d_in[8];

    float* out  = (float*)d_out;              // (B,N,C) = 1,572,864 floats
    float* aexp = out + (size_t)SEG;          // (B,HP,N,N) = 50,331,648 floats
    float* ws   = (float*)d_ws;               // q,k,v,head_out = 25.2 MB

    qkv_gemm   <<<dim3(36, 32), 256, 0, stream>>>(x, Wqk, Wv, ws);
    attn_expand<<<dim3(BB * NN), 256, 0, stream>>>(ws, Wexp, aexp);
    conv_red_pv<<<dim3(BB * NN), 256, 0, stream>>>(aexp, Wloc, bloc, Wred,
                                                   ws + VOFF, ws + HOFF);
    proj_gemm  <<<dim3(12, 32), 256, 0, stream>>>(ws + HOFF, Wproj, bproj, out);
}

// Round 2
// 1427.561 us; speedup vs baseline: 3.8254x; 3.8254x over previous
//
#include <hip/hip_runtime.h>
#include <math.h>

// Problem constants
#define BB    2
#define NN    1024
#define CC    768
#define HH    12
#define HPP   24
#define HD    64
#define SCALE 0.125f

// workspace layout (floats)
#define SEG   (2*1024*768)   // 1,572,864 floats per tensor
#define QOFF  0              // q_tok: (B*N, 768) token-major
#define KOFF  (SEG)          // k_t:   (B, 768, N) transposed
#define VOFF  (2*SEG)        // v:     (B, H, N, HD)
#define HOFF  (3*SEG)        // head_out: (B, N, C)

// ---------------------------------------------------------------------------
// Kernel 1: fused QKV projection.  x(2048,768) @ [Wqk;Wv]^T.
// Epilogue scatters: q -> token-major rows, k -> transposed (b,p,n), v -> (b,h,n,d).
// ---------------------------------------------------------------------------
__global__ __launch_bounds__(256)
void qkv_gemm(const float* __restrict__ x, const float* __restrict__ Wqk,
              const float* __restrict__ Wv, float* __restrict__ ws)
{
    __shared__ float As[16][68];   // [k][m], +4 pad keeps 16B alignment
    __shared__ float Bs[16][68];
    float* qtok = ws + QOFF;
    float* kt   = ws + KOFF;
    float* vws  = ws + VOFF;

    const int tid  = threadIdx.x;
    const int bn   = blockIdx.x;        // 0..35 (2304 cols / 64)
    const int bm   = blockIdx.y;        // 0..31 (2048 rows / 64)
    const int tx   = tid & 15, ty = tid >> 4;
    const int lrow = tid >> 2;          // 0..63
    const int lk   = (tid & 3) << 2;    // 0,4,8,12

    const int jrow = bn * 64 + lrow;    // weight row (output column)
    const float* Bsrc = (jrow < 1536) ? (Wqk + (size_t)jrow * 768)
                                      : (Wv  + (size_t)(jrow - 1536) * 768);
    const float* Asrc = x + (size_t)(bm * 64 + lrow) * 768;

    float c[4][4] = {};

    for (int k0 = 0; k0 < 768; k0 += 16) {
        float4 av = *(const float4*)(Asrc + k0 + lk);
        float4 bv = *(const float4*)(Bsrc + k0 + lk);
        __syncthreads();
        As[lk+0][lrow] = av.x; As[lk+1][lrow] = av.y;
        As[lk+2][lrow] = av.z; As[lk+3][lrow] = av.w;
        Bs[lk+0][lrow] = bv.x; Bs[lk+1][lrow] = bv.y;
        Bs[lk+2][lrow] = bv.z; Bs[lk+3][lrow] = bv.w;
        __syncthreads();
#pragma unroll
        for (int kk = 0; kk < 16; ++kk) {
            float a[4], b[4];
#pragma unroll
            for (int i = 0; i < 4; ++i) a[i] = As[kk][ty*4 + i];
#pragma unroll
            for (int j = 0; j < 4; ++j) b[j] = Bs[kk][tx*4 + j];
#pragma unroll
            for (int i = 0; i < 4; ++i)
#pragma unroll
                for (int j = 0; j < 4; ++j)
                    c[i][j] = fmaf(a[i], b[j], c[i][j]);
        }
    }

#pragma unroll
    for (int i = 0; i < 4; ++i) {
        const int t = bm*64 + ty*4 + i;      // token index 0..2047
        const int b = t >> 10, n = t & 1023;
#pragma unroll
        for (int j = 0; j < 4; ++j) {
            const int col = bn*64 + tx*4 + j;
            const float val = c[i][j];
            if (col < 768) {
                qtok[(size_t)t*768 + col] = val;
            } else if (col < 1536) {
                const int p = col - 768;                 // h*64+d
                kt[((size_t)(b*768 + p))*NN + n] = val;  // transposed
            } else {
                const int p = col - 1536;
                vws[(((size_t)b*HH + (p >> 6))*NN + n)*HD + (p & 63)] = val;
            }
        }
    }
}

// ---------------------------------------------------------------------------
// Kernel 2: per (b,n): 12 heads of QK^T logits -> softmax -> 1x1 expand
// (H->HP) -> write A_exp.  Attention row is REGISTER-RESIDENT: each thread
// owns 4 consecutive m for all 12 heads (float4 l[12]).  K reads coalesced
// via transposed layout.  No big LDS, no spills.
// ---------------------------------------------------------------------------
__global__ __launch_bounds__(256, 4)
void attn_expand(const float* __restrict__ qtok, const float* __restrict__ kt,
                 const float* __restrict__ Wexp, float* __restrict__ aexp)
{
    __shared__ __align__(16) float qs[CC];       // 3 KB: q row for this token
    __shared__ float wexp_s[HPP * HH];           // 1.2 KB
    __shared__ float redbuf[HH * 4];             // cross-wave partials

    const int tid  = threadIdx.x;
    const int lane = tid & 63, wid = tid >> 6;
    const int b = blockIdx.x >> 10;
    const int m4 = tid;                          // float4 column index 0..255

    if (tid < 192) ((float4*)qs)[tid] = ((const float4*)(qtok + (size_t)blockIdx.x * CC))[tid];
    for (int i = tid; i < HPP*HH; i += 256) wexp_s[i] = Wexp[i];
    __syncthreads();

    // ---- logits: l[h] = (q_h . K_h[:, m..m+3]) * SCALE -------------------
    float4 l[HH];
#pragma unroll
    for (int h = 0; h < HH; ++h) {
        float4 acc = {0.f, 0.f, 0.f, 0.f};
        const float4* kr = ((const float4*)kt) + (size_t)(b*768 + h*64) * 256 + m4;
#pragma unroll 16
        for (int d = 0; d < 64; ++d) {
            const float qv = qs[h*64 + d];
            const float4 kv = kr[(size_t)d * 256];
            acc.x = fmaf(kv.x, qv, acc.x);
            acc.y = fmaf(kv.y, qv, acc.y);
            acc.z = fmaf(kv.z, qv, acc.z);
            acc.w = fmaf(kv.w, qv, acc.w);
        }
        l[h].x = acc.x * SCALE; l[h].y = acc.y * SCALE;
        l[h].z = acc.z * SCALE; l[h].w = acc.w * SCALE;
    }

    // ---- softmax over m (row per head), cross-thread via shfl + LDS ------
#pragma unroll
    for (int h = 0; h < HH; ++h) {
        float t = fmaxf(fmaxf(l[h].x, l[h].y), fmaxf(l[h].z, l[h].w));
#pragma unroll
        for (int off = 32; off > 0; off >>= 1) t = fmaxf(t, __shfl_xor(t, off, 64));
        if (lane == 0) redbuf[h*4 + wid] = t;
    }
    __syncthreads();
    float mh[HH];
#pragma unroll
    for (int h = 0; h < HH; ++h)
        mh[h] = fmaxf(fmaxf(redbuf[h*4+0], redbuf[h*4+1]),
                      fmaxf(redbuf[h*4+2], redbuf[h*4+3]));
    __syncthreads();

#pragma unroll
    for (int h = 0; h < HH; ++h) {
        l[h].x = __expf(l[h].x - mh[h]);
        l[h].y = __expf(l[h].y - mh[h]);
        l[h].z = __expf(l[h].z - mh[h]);
        l[h].w = __expf(l[h].w - mh[h]);
        float s = (l[h].x + l[h].y) + (l[h].z + l[h].w);
#pragma unroll
        for (int off = 32; off > 0; off >>= 1) s += __shfl_xor(s, off, 64);
        if (lane == 0) redbuf[h*4 + wid] = s;
    }
    __syncthreads();
#pragma unroll
    for (int h = 0; h < HH; ++h) {
        const float inv = 1.f / (redbuf[h*4+0] + redbuf[h*4+1] +
                                 redbuf[h*4+2] + redbuf[h*4+3]);
        l[h].x *= inv; l[h].y *= inv; l[h].z *= inv; l[h].w *= inv;
    }

    // ---- expand H -> HP, write A_exp (float4 coalesced) ------------------
    float4* aout = ((float4*)aexp) + ((size_t)b*HPP*NN + (blockIdx.x & 1023)) * 256;
    // row o lives at ((b*HPP+o)*NN + n)*NN floats -> float4 base above + o*NN*256
#pragma unroll 4
    for (int o = 0; o < HPP; ++o) {
        float4 acc = {0.f, 0.f, 0.f, 0.f};
#pragma unroll
        for (int h = 0; h < HH; ++h) {
            const float w = wexp_s[o*HH + h];
            acc.x = fmaf(w, l[h].x, acc.x);
            acc.y = fmaf(w, l[h].y, acc.y);
            acc.z = fmaf(w, l[h].z, acc.z);
            acc.w = fmaf(w, l[h].w, acc.w);
        }
        aout[(size_t)o * NN * 256 + m4] = acc;
    }
}

// ---------------------------------------------------------------------------
// Kernel 3: per (b,n): depthwise 3x3 conv (+bias,ReLU) over A_exp, reduce
// HP->H (*SCALE folded into wred), softmax, then attn2 @ v -> head_out in ws.
// ---------------------------------------------------------------------------
__global__ __launch_bounds__(256)
void conv_red_pv(const float* __restrict__ aexp, const float* __restrict__ Wloc,
                 const float* __restrict__ bloc, const float* __restrict__ Wred,
                 const float* __restrict__ vws, float* __restrict__ hout)
{
    __shared__ float ared[HH * NN];     // 48 KB (A_red, then attn2 in-place)
    __shared__ float rows[3][NN + 2];   // 12.3 KB, zero-padded edges
    __shared__ float wloc_s[HPP * 9];
    __shared__ float bloc_s[HPP];
    __shared__ float wred_s[HH * HPP];
    __shared__ float red_s[4];

    const int tid = threadIdx.x;
    const int b = blockIdx.x >> 10, n = blockIdx.x & 1023;

    for (int idx = tid; idx < HH*NN; idx += 256) ared[idx] = 0.f;
    for (int idx = tid; idx < HPP*9; idx += 256) wloc_s[idx] = Wloc[idx];
    if (tid < HPP) bloc_s[tid] = bloc[tid];
    for (int idx = tid; idx < HH*HPP; idx += 256) wred_s[idx] = Wred[idx] * SCALE;
    if (tid < 3) { rows[tid][0] = 0.f; rows[tid][NN+1] = 0.f; }
    __syncthreads();

    for (int o = 0; o < HPP; ++o) {
        for (int r = 0; r < 3; ++r) {
            const int nr = n - 1 + r;
            if (nr >= 0 && nr < NN) {
                const float* src = aexp + (((size_t)b*HPP + o)*NN + nr)*NN;
#pragma unroll
                for (int m0 = 0; m0 < 4; ++m0) rows[r][1 + m0*256 + tid] = src[m0*256 + tid];
            } else {
#pragma unroll
                for (int m0 = 0; m0 < 4; ++m0) rows[r][1 + m0*256 + tid] = 0.f;
            }
        }
        __syncthreads();

        const float* w = wloc_s + o*9;
        const float bbias = bloc_s[o];
        float wr[HH];
#pragma unroll
        for (int i = 0; i < HH; ++i) wr[i] = wred_s[i*HPP + o];

#pragma unroll
        for (int m0 = 0; m0 < 4; ++m0) {
            const int m = m0*256 + tid;
            float acc = bbias;
            acc = fmaf(rows[0][m+0], w[0], acc);
            acc = fmaf(rows[0][m+1], w[1], acc);
            acc = fmaf(rows[0][m+2], w[2], acc);
            acc = fmaf(rows[1][m+0], w[3], acc);
            acc = fmaf(rows[1][m+1], w[4], acc);
            acc = fmaf(rows[1][m+2], w[5], acc);
            acc = fmaf(rows[2][m+0], w[6], acc);
            acc = fmaf(rows[2][m+1], w[7], acc);
            acc = fmaf(rows[2][m+2], w[8], acc);
            const float val = fmaxf(acc, 0.f);
#pragma unroll
            for (int i = 0; i < HH; ++i)
                ared[i*NN + m] = fmaf(wr[i], val, ared[i*NN + m]);
        }
        __syncthreads();
    }

    // softmax per head row of ared
    for (int i = 0; i < HH; ++i) {
        float lm = -1e30f;
#pragma unroll
        for (int m0 = 0; m0 < 4; ++m0)
            lm = fmaxf(lm, ared[i*NN + m0*256 + tid]);
        for (int off = 32; off > 0; off >>= 1) lm = fmaxf(lm, __shfl_xor(lm, off, 64));
        if ((tid & 63) == 0) red_s[tid >> 6] = lm;
        __syncthreads();
        const float rowmax = fmaxf(fmaxf(red_s[0], red_s[1]), fmaxf(red_s[2], red_s[3]));
        __syncthreads();

        float ls = 0.f;
#pragma unroll
        for (int m0 = 0; m0 < 4; ++m0) {
            const int idx = i*NN + m0*256 + tid;
            const float e = __expf(ared[idx] - rowmax);
            ared[idx] = e; ls += e;
        }
        for (int off = 32; off > 0; off >>= 1) ls += __shfl_xor(ls, off, 64);
        if ((tid & 63) == 0) red_s[tid >> 6] = ls;
        __syncthreads();
        const float inv = 1.f / (red_s[0] + red_s[1] + red_s[2] + red_s[3]);
        __syncthreads();
#pragma unroll
        for (int m0 = 0; m0 < 4; ++m0)
            ared[i*NN + m0*256 + tid] *= inv;
    }
    __syncthreads();

    // PV: lanes over d (coalesced v), wave-uniform attn2 broadcast from LDS
    const int g = tid >> 6, d = tid & 63;
    const int i0 = g, i1 = g + 4, i2 = g + 8;
    const float* v0 = vws + (((size_t)b*HH + i0)*NN)*HD + d;
    const float* v1 = vws + (((size_t)b*HH + i1)*NN)*HD + d;
    const float* v2 = vws + (((size_t)b*HH + i2)*NN)*HD + d;
    float acc0 = 0.f, acc1 = 0.f, acc2 = 0.f;
#pragma unroll 4
    for (int m = 0; m < NN; ++m) {
        acc0 = fmaf(ared[i0*NN + m], v0[(size_t)m*HD], acc0);
        acc1 = fmaf(ared[i1*NN + m], v1[(size_t)m*HD], acc1);
        acc2 = fmaf(ared[i2*NN + m], v2[(size_t)m*HD], acc2);
    }
    const size_t base = ((size_t)(b*NN + n)) * CC;
    hout[base + i0*HD + d] = acc0;
    hout[base + i1*HD + d] = acc1;
    hout[base + i2*HD + d] = acc2;
}

// ---------------------------------------------------------------------------
// Kernel 4: final projection  out = head_out @ Wproj^T + bias
// ---------------------------------------------------------------------------
__global__ __launch_bounds__(256)
void proj_gemm(const float* __restrict__ A, const float* __restrict__ Wp,
               const float* __restrict__ bias, float* __restrict__ out)
{
    __shared__ float As[16][68];
    __shared__ float Bs[16][68];

    const int tid  = threadIdx.x;
    const int bn   = blockIdx.x;   // 0..11
    const int bm   = blockIdx.y;   // 0..31
    const int tx   = tid & 15, ty = tid >> 4;
    const int lrow = tid >> 2;
    const int lk   = (tid & 3) << 2;

    const float* Asrc = A  + (size_t)(bm*64 + lrow) * 768;
    const float* Bsrc = Wp + (size_t)(bn*64 + lrow) * 768;

    float c[4][4] = {};

    for (int k0 = 0; k0 < 768; k0 += 16) {
        float4 av = *(const float4*)(Asrc + k0 + lk);
        float4 bv = *(const float4*)(Bsrc + k0 + lk);
        __syncthreads();
        As[lk+0][lrow] = av.x; As[lk+1][lrow] = av.y;
        As[lk+2][lrow] = av.z; As[lk+3][lrow] = av.w;
        Bs[lk+0][lrow] = bv.x; Bs[lk+1][lrow] = bv.y;
        Bs[lk+2][lrow] = bv.z; Bs[lk+3][lrow] = bv.w;
        __syncthreads();
#pragma unroll
        for (int kk = 0; kk < 16; ++kk) {
            float a[4], b[4];
#pragma unroll
            for (int i = 0; i < 4; ++i) a[i] = As[kk][ty*4 + i];
#pragma unroll
            for (int j = 0; j < 4; ++j) b[j] = Bs[kk][tx*4 + j];
#pragma unroll
            for (int i = 0; i < 4; ++i)
#pragma unroll
                for (int j = 0; j < 4; ++j)
                    c[i][j] = fmaf(a[i], b[j], c[i][j]);
        }
    }

#pragma unroll
    for (int i = 0; i < 4; ++i) {
        const int t = bm*64 + ty*4 + i;
#pragma unroll
        for (int j = 0; j < 4; ++j) {
            const int col = bn*64 + tx*4 + j;
            out[(size_t)t*768 + col] = c[i][j] + bias[col];
        }
    }
}

// ---------------------------------------------------------------------------
extern "C" void kernel_launch(void* const* d_in, const int* in_sizes, int n_in,
                              void* d_out, int out_size, void* d_ws, size_t ws_size,
                              hipStream_t stream)
{
    const float* x     = (const float*)d_in[0];
    const float* Wqk   = (const float*)d_in[1];
    const float* Wv    = (const float*)d_in[2];
    const float* Wexp  = (const float*)d_in[3];
    const float* Wloc  = (const float*)d_in[4];
    const float* bloc  = (const float*)d_in[5];
    const float* Wred  = (const float*)d_in[6];
    const float* Wproj = (const float*)d_in[7];
    const float* bproj = (const float*)d_in[8];

    float* out  = (float*)d_out;              // (B,N,C) = 1,572,864 floats
    float* aexp = out + (size_t)SEG;          // (B,HP,N,N) = 50,331,648 floats
    float* ws   = (float*)d_ws;               // q_tok, k_t, v, head_out = 25.2 MB

    qkv_gemm   <<<dim3(36, 32), 256, 0, stream>>>(x, Wqk, Wv, ws);
    attn_expand<<<dim3(BB * NN), 256, 0, stream>>>(ws + QOFF, ws + KOFF, Wexp, aexp);
    conv_red_pv<<<dim3(BB * NN), 256, 0, stream>>>(aexp, Wloc, bloc, Wred,
                                                   ws + VOFF, ws + HOFF);
    proj_gemm  <<<dim3(12, 32), 256, 0, stream>>>(ws + HOFF, Wproj, bproj, out);
}

// Round 3
// 1053.499 us; speedup vs baseline: 5.1837x; 1.3551x over previous
//
#include <hip/hip_runtime.h>
#include <math.h>

// Problem constants
#define BB    2
#define NN    1024
#define CC    768
#define HH    12
#define HPP   24
#define HD    64
#define SCALE 0.125f

// workspace layout (floats)
#define SEG   (2*1024*768)   // 1,572,864 floats per tensor
#define QOFF  0              // q_tok: (B*N, 768) token-major
#define KOFF  (SEG)          // k_t:   (B, 768, N) transposed
#define VOFF  (2*SEG)        // v:     (B, H, N, HD)
#define HOFF  (3*SEG)        // head_out: (B, N, C)

// ---------------------------------------------------------------------------
// Kernel 1: fused QKV projection.  x(2048,768) @ [Wqk;Wv]^T.
// Epilogue scatters: q -> token-major rows, k -> transposed (b,p,n), v -> (b,h,n,d).
// ---------------------------------------------------------------------------
__global__ __launch_bounds__(256)
void qkv_gemm(const float* __restrict__ x, const float* __restrict__ Wqk,
              const float* __restrict__ Wv, float* __restrict__ ws)
{
    __shared__ float As[16][68];   // [k][m], +4 pad keeps 16B alignment
    __shared__ float Bs[16][68];
    float* qtok = ws + QOFF;
    float* kt   = ws + KOFF;
    float* vws  = ws + VOFF;

    const int tid  = threadIdx.x;
    const int bn   = blockIdx.x;        // 0..35 (2304 cols / 64)
    const int bm   = blockIdx.y;        // 0..31 (2048 rows / 64)
    const int tx   = tid & 15, ty = tid >> 4;
    const int lrow = tid >> 2;          // 0..63
    const int lk   = (tid & 3) << 2;    // 0,4,8,12

    const int jrow = bn * 64 + lrow;    // weight row (output column)
    const float* Bsrc = (jrow < 1536) ? (Wqk + (size_t)jrow * 768)
                                      : (Wv  + (size_t)(jrow - 1536) * 768);
    const float* Asrc = x + (size_t)(bm * 64 + lrow) * 768;

    float c[4][4] = {};

    for (int k0 = 0; k0 < 768; k0 += 16) {
        float4 av = *(const float4*)(Asrc + k0 + lk);
        float4 bv = *(const float4*)(Bsrc + k0 + lk);
        __syncthreads();
        As[lk+0][lrow] = av.x; As[lk+1][lrow] = av.y;
        As[lk+2][lrow] = av.z; As[lk+3][lrow] = av.w;
        Bs[lk+0][lrow] = bv.x; Bs[lk+1][lrow] = bv.y;
        Bs[lk+2][lrow] = bv.z; Bs[lk+3][lrow] = bv.w;
        __syncthreads();
#pragma unroll
        for (int kk = 0; kk < 16; ++kk) {
            float a[4], b[4];
#pragma unroll
            for (int i = 0; i < 4; ++i) a[i] = As[kk][ty*4 + i];
#pragma unroll
            for (int j = 0; j < 4; ++j) b[j] = Bs[kk][tx*4 + j];
#pragma unroll
            for (int i = 0; i < 4; ++i)
#pragma unroll
                for (int j = 0; j < 4; ++j)
                    c[i][j] = fmaf(a[i], b[j], c[i][j]);
        }
    }

#pragma unroll
    for (int i = 0; i < 4; ++i) {
        const int t = bm*64 + ty*4 + i;      // token index 0..2047
        const int b = t >> 10, n = t & 1023;
#pragma unroll
        for (int j = 0; j < 4; ++j) {
            const int col = bn*64 + tx*4 + j;
            const float val = c[i][j];
            if (col < 768) {
                qtok[(size_t)t*768 + col] = val;
            } else if (col < 1536) {
                const int p = col - 768;                 // h*64+d
                kt[((size_t)(b*768 + p))*NN + n] = val;  // transposed
            } else {
                const int p = col - 1536;
                vws[(((size_t)b*HH + (p >> 6))*NN + n)*HD + (p & 63)] = val;
            }
        }
    }
}

// ---------------------------------------------------------------------------
// Kernel 2: per (b,n): 12 heads of QK^T logits -> softmax -> 1x1 expand
// (H->HP) -> write A_exp.  Attention row register-resident (float4 l[12]).
// ---------------------------------------------------------------------------
__global__ __launch_bounds__(256, 4)
void attn_expand(const float* __restrict__ qtok, const float* __restrict__ kt,
                 const float* __restrict__ Wexp, float* __restrict__ aexp)
{
    __shared__ __align__(16) float qs[CC];       // 3 KB: q row for this token
    __shared__ float wexp_s[HPP * HH];           // 1.2 KB
    __shared__ float redbuf[HH * 4];             // cross-wave partials

    const int tid  = threadIdx.x;
    const int lane = tid & 63, wid = tid >> 6;
    const int b = blockIdx.x >> 10;
    const int m4 = tid;                          // float4 column index 0..255

    if (tid < 192) ((float4*)qs)[tid] = ((const float4*)(qtok + (size_t)blockIdx.x * CC))[tid];
    for (int i = tid; i < HPP*HH; i += 256) wexp_s[i] = Wexp[i];
    __syncthreads();

    // ---- logits: l[h] = (q_h . K_h[:, m..m+3]) * SCALE -------------------
    float4 l[HH];
#pragma unroll
    for (int h = 0; h < HH; ++h) {
        float4 acc = {0.f, 0.f, 0.f, 0.f};
        const float4* kr = ((const float4*)kt) + (size_t)(b*768 + h*64) * 256 + m4;
#pragma unroll 16
        for (int d = 0; d < 64; ++d) {
            const float qv = qs[h*64 + d];
            const float4 kv = kr[(size_t)d * 256];
            acc.x = fmaf(kv.x, qv, acc.x);
            acc.y = fmaf(kv.y, qv, acc.y);
            acc.z = fmaf(kv.z, qv, acc.z);
            acc.w = fmaf(kv.w, qv, acc.w);
        }
        l[h].x = acc.x * SCALE; l[h].y = acc.y * SCALE;
        l[h].z = acc.z * SCALE; l[h].w = acc.w * SCALE;
    }

    // ---- softmax over m (row per head), cross-thread via shfl + LDS ------
#pragma unroll
    for (int h = 0; h < HH; ++h) {
        float t = fmaxf(fmaxf(l[h].x, l[h].y), fmaxf(l[h].z, l[h].w));
#pragma unroll
        for (int off = 32; off > 0; off >>= 1) t = fmaxf(t, __shfl_xor(t, off, 64));
        if (lane == 0) redbuf[h*4 + wid] = t;
    }
    __syncthreads();
    float mh[HH];
#pragma unroll
    for (int h = 0; h < HH; ++h)
        mh[h] = fmaxf(fmaxf(redbuf[h*4+0], redbuf[h*4+1]),
                      fmaxf(redbuf[h*4+2], redbuf[h*4+3]));
    __syncthreads();

#pragma unroll
    for (int h = 0; h < HH; ++h) {
        l[h].x = __expf(l[h].x - mh[h]);
        l[h].y = __expf(l[h].y - mh[h]);
        l[h].z = __expf(l[h].z - mh[h]);
        l[h].w = __expf(l[h].w - mh[h]);
        float s = (l[h].x + l[h].y) + (l[h].z + l[h].w);
#pragma unroll
        for (int off = 32; off > 0; off >>= 1) s += __shfl_xor(s, off, 64);
        if (lane == 0) redbuf[h*4 + wid] = s;
    }
    __syncthreads();
#pragma unroll
    for (int h = 0; h < HH; ++h) {
        const float inv = 1.f / (redbuf[h*4+0] + redbuf[h*4+1] +
                                 redbuf[h*4+2] + redbuf[h*4+3]);
        l[h].x *= inv; l[h].y *= inv; l[h].z *= inv; l[h].w *= inv;
    }

    // ---- expand H -> HP, write A_exp (float4 coalesced) ------------------
    float4* aout = ((float4*)aexp) + ((size_t)b*HPP*NN + (blockIdx.x & 1023)) * 256;
#pragma unroll 4
    for (int o = 0; o < HPP; ++o) {
        float4 acc = {0.f, 0.f, 0.f, 0.f};
#pragma unroll
        for (int h = 0; h < HH; ++h) {
            const float w = wexp_s[o*HH + h];
            acc.x = fmaf(w, l[h].x, acc.x);
            acc.y = fmaf(w, l[h].y, acc.y);
            acc.z = fmaf(w, l[h].z, acc.z);
            acc.w = fmaf(w, l[h].w, acc.w);
        }
        aout[(size_t)o * NN * 256 + m4] = acc;
    }
}

// ---------------------------------------------------------------------------
// Kernel 3 (v2): per (b,n): depthwise 3x3 conv (+bias,ReLU) over A_exp,
// HP->H reduce into REGISTER accumulators (float4 acc[12]), softmax in regs,
// probs -> LDS (aliased over the row staging buffers), then PV with float4
// v loads.  Double-buffered row staging, 1 barrier/channel.
// ---------------------------------------------------------------------------
#define ROWSTR 1040            // 4 front pad + 1024 data + tail pad (16B aligned)
#define BUFSTR (3*ROWSTR)      // 3 rows per buffer

__global__ __launch_bounds__(256, 3)
void conv_red_pv(const float* __restrict__ aexp, const float* __restrict__ Wloc,
                 const float* __restrict__ bloc, const float* __restrict__ Wred,
                 const float* __restrict__ vws, float* __restrict__ hout)
{
    __shared__ float smem[HH * NN];     // 48 KB: rows dbuf (2*3120) then attn2 probs
    __shared__ float wloc_s[HPP * 9];
    __shared__ float bloc_s[HPP];
    __shared__ float wred_s[HH * HPP];
    __shared__ float redbuf[HH * 4];

    const int tid  = threadIdx.x;
    const int lane = tid & 63, wid = tid >> 6;
    const int b = blockIdx.x >> 10, n = blockIdx.x & 1023;

    for (int idx = tid; idx < HPP*9; idx += 256) wloc_s[idx] = Wloc[idx];
    if (tid < HPP) bloc_s[tid] = bloc[tid];
    for (int idx = tid; idx < HH*HPP; idx += 256) wred_s[idx] = Wred[idx] * SCALE;
    if (tid < 6) {                       // zero halo cells, both buffers x 3 rows
        const int bu = tid >> 1, r = tid - bu*2 + bu;  // not a clean map; do explicit:
    }
    // explicit halo zero: 2 buffers x 3 rows x 2 cells = 12 cells
    if (tid < 12) {
        const int bu = tid / 6, rr = (tid % 6) / 2, cell = tid & 1;
        smem[bu*BUFSTR + rr*ROWSTR + (cell ? 1028 : 3)] = 0.f;
    }

    // row validity (conv SAME padding at n edges)
    const bool rv[3] = { n > 0, true, n < NN-1 };

    // ---- prefetch channel 0 ----------------------------------------------
    float4 ld[3];
#pragma unroll
    for (int r = 0; r < 3; ++r) {
        if (rv[r]) {
            const size_t row = ((size_t)(b*HPP + 0)*NN + (n-1+r));
            ld[r] = ((const float4*)aexp)[row*256 + tid];
        } else ld[r] = make_float4(0.f,0.f,0.f,0.f);
    }
#pragma unroll
    for (int r = 0; r < 3; ++r)
        *((float4*)(smem + 0*BUFSTR + r*ROWSTR + 4) + tid) = ld[r];

    float4 acc[HH];
#pragma unroll
    for (int i = 0; i < HH; ++i) acc[i] = make_float4(0.f,0.f,0.f,0.f);

    // ---- conv + reduce loop ----------------------------------------------
    for (int o = 0; o < HPP; ++o) {
        const int buf = o & 1;
        if (o < HPP-1) {
#pragma unroll
            for (int r = 0; r < 3; ++r) {
                if (rv[r]) {
                    const size_t row = ((size_t)(b*HPP + (o+1))*NN + (n-1+r));
                    ld[r] = ((const float4*)aexp)[row*256 + tid];
                } else ld[r] = make_float4(0.f,0.f,0.f,0.f);
            }
        }
        __syncthreads();   // staging of channel o visible to all

        const float* w  = wloc_s + o*9;
        const float  bb = bloc_s[o];
        const float* r0 = smem + buf*BUFSTR + 0*ROWSTR + 3 + 4*tid;
        const float* r1 = smem + buf*BUFSTR + 1*ROWSTR + 3 + 4*tid;
        const float* r2 = smem + buf*BUFSTR + 2*ROWSTR + 3 + 4*tid;

        float val[4];
#pragma unroll
        for (int j = 0; j < 4; ++j) {
            float a = bb;
            a = fmaf(r0[j+0], w[0], a); a = fmaf(r0[j+1], w[1], a); a = fmaf(r0[j+2], w[2], a);
            a = fmaf(r1[j+0], w[3], a); a = fmaf(r1[j+1], w[4], a); a = fmaf(r1[j+2], w[5], a);
            a = fmaf(r2[j+0], w[6], a); a = fmaf(r2[j+1], w[7], a); a = fmaf(r2[j+2], w[8], a);
            val[j] = fmaxf(a, 0.f);
        }
#pragma unroll
        for (int i = 0; i < HH; ++i) {
            const float wr = wred_s[i*HPP + o];
            acc[i].x = fmaf(wr, val[0], acc[i].x);
            acc[i].y = fmaf(wr, val[1], acc[i].y);
            acc[i].z = fmaf(wr, val[2], acc[i].z);
            acc[i].w = fmaf(wr, val[3], acc[i].w);
        }
        if (o < HPP-1) {
#pragma unroll
            for (int r = 0; r < 3; ++r)
                *((float4*)(smem + (buf^1)*BUFSTR + r*ROWSTR + 4) + tid) = ld[r];
        }
    }

    // ---- softmax over m (register rows, shfl + LDS cross-wave) -----------
#pragma unroll
    for (int i = 0; i < HH; ++i) {
        float t = fmaxf(fmaxf(acc[i].x, acc[i].y), fmaxf(acc[i].z, acc[i].w));
#pragma unroll
        for (int off = 32; off > 0; off >>= 1) t = fmaxf(t, __shfl_xor(t, off, 64));
        if (lane == 0) redbuf[i*4 + wid] = t;
    }
    __syncthreads();   // also separates last conv LDS reads from prob writes
    float mh[HH];
#pragma unroll
    for (int i = 0; i < HH; ++i)
        mh[i] = fmaxf(fmaxf(redbuf[i*4+0], redbuf[i*4+1]),
                      fmaxf(redbuf[i*4+2], redbuf[i*4+3]));
    __syncthreads();

#pragma unroll
    for (int i = 0; i < HH; ++i) {
        acc[i].x = __expf(acc[i].x - mh[i]);
        acc[i].y = __expf(acc[i].y - mh[i]);
        acc[i].z = __expf(acc[i].z - mh[i]);
        acc[i].w = __expf(acc[i].w - mh[i]);
        float s = (acc[i].x + acc[i].y) + (acc[i].z + acc[i].w);
#pragma unroll
        for (int off = 32; off > 0; off >>= 1) s += __shfl_xor(s, off, 64);
        if (lane == 0) redbuf[i*4 + wid] = s;
    }
    __syncthreads();
#pragma unroll
    for (int i = 0; i < HH; ++i) {
        const float inv = 1.f / (redbuf[i*4+0] + redbuf[i*4+1] +
                                 redbuf[i*4+2] + redbuf[i*4+3]);
        acc[i].x *= inv; acc[i].y *= inv; acc[i].z *= inv; acc[i].w *= inv;
        ((float4*)smem)[i*256 + tid] = acc[i];   // probs into LDS (alias rows)
    }
    __syncthreads();

    // ---- PV: wave owns 3 heads; lanes = (mg,dq); float4 v loads ----------
    const int mg = lane >> 4, dq = lane & 15;
    const size_t outbase = ((size_t)(b*NN + n)) * CC;
#pragma unroll
    for (int t = 0; t < 3; ++t) {
        const int i = wid*3 + t;
        const float4* vp = (const float4*)(vws + (((size_t)b*HH + i)*NN)*HD) + dq;
        const float*  pr = smem + i*NN + mg;
        float4 a4 = make_float4(0.f,0.f,0.f,0.f);
#pragma unroll 8
        for (int m0 = 0; m0 < NN; m0 += 4) {
            const float  p  = pr[m0];
            const float4 vv = vp[(size_t)(m0+mg)*16];
            a4.x = fmaf(p, vv.x, a4.x);
            a4.y = fmaf(p, vv.y, a4.y);
            a4.z = fmaf(p, vv.z, a4.z);
            a4.w = fmaf(p, vv.w, a4.w);
        }
        a4.x += __shfl_xor(a4.x, 16, 64); a4.x += __shfl_xor(a4.x, 32, 64);
        a4.y += __shfl_xor(a4.y, 16, 64); a4.y += __shfl_xor(a4.y, 32, 64);
        a4.z += __shfl_xor(a4.z, 16, 64); a4.z += __shfl_xor(a4.z, 32, 64);
        a4.w += __shfl_xor(a4.w, 16, 64); a4.w += __shfl_xor(a4.w, 32, 64);
        if (mg == 0)
            ((float4*)(hout + outbase + i*HD))[dq] = a4;
    }
}

// ---------------------------------------------------------------------------
// Kernel 4: final projection  out = head_out @ Wproj^T + bias
// ---------------------------------------------------------------------------
__global__ __launch_bounds__(256)
void proj_gemm(const float* __restrict__ A, const float* __restrict__ Wp,
               const float* __restrict__ bias, float* __restrict__ out)
{
    __shared__ float As[16][68];
    __shared__ float Bs[16][68];

    const int tid  = threadIdx.x;
    const int bn   = blockIdx.x;   // 0..11
    const int bm   = blockIdx.y;   // 0..31
    const int tx   = tid & 15, ty = tid >> 4;
    const int lrow = tid >> 2;
    const int lk   = (tid & 3) << 2;

    const float* Asrc = A  + (size_t)(bm*64 + lrow) * 768;
    const float* Bsrc = Wp + (size_t)(bn*64 + lrow) * 768;

    float c[4][4] = {};

    for (int k0 = 0; k0 < 768; k0 += 16) {
        float4 av = *(const float4*)(Asrc + k0 + lk);
        float4 bv = *(const float4*)(Bsrc + k0 + lk);
        __syncthreads();
        As[lk+0][lrow] = av.x; As[lk+1][lrow] = av.y;
        As[lk+2][lrow] = av.z; As[lk+3][lrow] = av.w;
        Bs[lk+0][lrow] = bv.x; Bs[lk+1][lrow] = bv.y;
        Bs[lk+2][lrow] = bv.z; Bs[lk+3][lrow] = bv.w;
        __syncthreads();
#pragma unroll
        for (int kk = 0; kk < 16; ++kk) {
            float a[4], b[4];
#pragma unroll
            for (int i = 0; i < 4; ++i) a[i] = As[kk][ty*4 + i];
#pragma unroll
            for (int j = 0; j < 4; ++j) b[j] = Bs[kk][tx*4 + j];
#pragma unroll
            for (int i = 0; i < 4; ++i)
#pragma unroll
                for (int j = 0; j < 4; ++j)
                    c[i][j] = fmaf(a[i], b[j], c[i][j]);
        }
    }

#pragma unroll
    for (int i = 0; i < 4; ++i) {
        const int t = bm*64 + ty*4 + i;
#pragma unroll
        for (int j = 0; j < 4; ++j) {
            const int col = bn*64 + tx*4 + j;
            out[(size_t)t*768 + col] = c[i][j] + bias[col];
        }
    }
}

// ---------------------------------------------------------------------------
extern "C" void kernel_launch(void* const* d_in, const int* in_sizes, int n_in,
                              void* d_out, int out_size, void* d_ws, size_t ws_size,
                              hipStream_t stream)
{
    const float* x     = (const float*)d_in[0];
    const float* Wqk   = (const float*)d_in[1];
    const float* Wv    = (const float*)d_in[2];
    const float* Wexp  = (const float*)d_in[3];
    const float* Wloc  = (const float*)d_in[4];
    const float* bloc  = (const float*)d_in[5];
    const float* Wred  = (const float*)d_in[6];
    const float* Wproj = (const float*)d_in[7];
    const float* bproj = (const float*)d_in[8];

    float* out  = (float*)d_out;              // (B,N,C) = 1,572,864 floats
    float* aexp = out + (size_t)SEG;          // (B,HP,N,N) = 50,331,648 floats
    float* ws   = (float*)d_ws;               // q_tok, k_t, v, head_out = 25.2 MB

    qkv_gemm   <<<dim3(36, 32), 256, 0, stream>>>(x, Wqk, Wv, ws);
    attn_expand<<<dim3(BB * NN), 256, 0, stream>>>(ws + QOFF, ws + KOFF, Wexp, aexp);
    conv_red_pv<<<dim3(BB * NN), 256, 0, stream>>>(aexp, Wloc, bloc, Wred,
                                                   ws + VOFF, ws + HOFF);
    proj_gemm  <<<dim3(12, 32), 256, 0, stream>>>(ws + HOFF, Wproj, bproj, out);
}